// Round 5
// baseline (688.137 us; speedup 1.0000x reference)
//
#include <hip/hip_runtime.h>
#include <hip/hip_bf16.h>
#include <math.h>

// ---------------------------------------------------------------------------
// BiFormerAttention: B=4, N=2048, C=768, H=12, hd=64, keep=1024
// GEMMs: MFMA f16 3-product split (fp32-grade -> top-k set preserved).
// Attention: fixed-ref-50 softmax (= exact softmax after clip +-50),
//   QK = Qhi(f16) x K(f16 hi/lo) 2-product; PV = P(bf16) x V(bf16 hi/lo)
//   2-product. Deferred row-sum (one reduce at end, no online rescale).
// ---------------------------------------------------------------------------

#define B_  4
#define N_  2048
#define C_  768
#define H_  12
#define HD_ 64
#define KEEP_ 1024
#define BH_ (B_ * H_)
#define GK  768   // K dim of both big GEMMs

typedef __attribute__((ext_vector_type(8))) short short8v;     // 8 bf16
typedef __attribute__((ext_vector_type(4))) float f32x4;       // MFMA C/D
typedef __attribute__((ext_vector_type(8))) _Float16 f16x8;    // 8 fp16
typedef __attribute__((ext_vector_type(4))) _Float16 f16x4;

__device__ inline unsigned short f2bf(float f) {               // RNE f32->bf16
    unsigned u = __float_as_uint(f);
    unsigned r = (u + 0x7fffu + ((u >> 16) & 1u)) >> 16;
    return (unsigned short)r;
}
__device__ inline float bf2f(unsigned short h) {
    return __uint_as_float(((unsigned)h) << 16);
}

__device__ inline void gload16(const _Float16* g, const _Float16* l) {
    __builtin_amdgcn_global_load_lds(
        (const __attribute__((address_space(1))) unsigned int*)(g),
        (__attribute__((address_space(3))) unsigned int*)(l), 16, 0, 0);
}

// ---------------- elementwise split: fp32 -> f16 hi + f16 lo ----------------
__global__ __launch_bounds__(256) void split4_kernel(
    const float* __restrict__ in, _Float16* __restrict__ hi,
    _Float16* __restrict__ lo, int n4)
{
    int i = blockIdx.x * 256 + threadIdx.x;
    if (i >= n4) return;
    float4 v = reinterpret_cast<const float4*>(in)[i];
    f16x4 h, l;
    h[0] = (_Float16)v.x; l[0] = (_Float16)(v.x - (float)h[0]);
    h[1] = (_Float16)v.y; l[1] = (_Float16)(v.y - (float)h[1]);
    h[2] = (_Float16)v.z; l[2] = (_Float16)(v.z - (float)h[2]);
    h[3] = (_Float16)v.w; l[3] = (_Float16)(v.w - (float)h[3]);
    reinterpret_cast<f16x4*>(hi)[i] = h;
    reinterpret_cast<f16x4*>(lo)[i] = l;
}

// ---------------- transpose + split: W[K][N] fp32 -> T[N][GK] f16 hi/lo -----
__global__ __launch_bounds__(256) void tsplit_kernel(
    const float* __restrict__ W, _Float16* __restrict__ Th,
    _Float16* __restrict__ Tl, int N)
{
    __shared__ float t[32][33];
    int n0 = blockIdx.x * 32, k0 = blockIdx.y * 32;
    int r = threadIdx.x >> 3, c4 = (threadIdx.x & 7) << 2;
    float4 v = *reinterpret_cast<const float4*>(&W[(size_t)(k0 + r) * N + n0 + c4]);
    t[r][c4 + 0] = v.x; t[r][c4 + 1] = v.y; t[r][c4 + 2] = v.z; t[r][c4 + 3] = v.w;
    __syncthreads();
#pragma unroll
    for (int j = 0; j < 4; ++j) {
        float val = t[c4 + j][r];                 // = W[k0+c4+j][n0+r]
        _Float16 h = (_Float16)val;
        size_t o = (size_t)(n0 + r) * GK + k0 + c4 + j;
        Th[o] = h;
        Tl[o] = (_Float16)(val - (float)h);
    }
}

// ---------------- MFMA split-f16 GEMM: C[M][N] = A[M][GK] * B^T[N][GK] ------
template <bool EPI>
__global__ __launch_bounds__(256, 2) void mfma_gemm(
    const _Float16* __restrict__ Ah, const _Float16* __restrict__ Al,
    const _Float16* __restrict__ Bh, const _Float16* __restrict__ Bl,
    float* __restrict__ C, int N, const float* __restrict__ bias,
    int gx, int cpx)
{
    __shared__ _Float16 lds[4][128 * 64];   // Ah,Al,Bh,Bl tiles (64 KiB)

    const int sb = ((int)blockIdx.x & 7) * cpx + ((int)blockIdx.x >> 3);
    const int bx = sb % gx, by = sb / gx;
    const int row0 = by * 128, col0 = bx * 128;

    const int tid = threadIdx.x;
    const int wave = tid >> 6, lane = tid & 63;
    const int fr = lane & 15, grp = lane >> 4;
    const int wr = wave >> 1, wc = wave & 1;

    const int dr = lane >> 3, ch = lane & 7;
    const int sc = (ch ^ dr) * 8;           // pre-swizzled source chunk

    const _Float16* srcs[4] = {
        Ah + (size_t)row0 * GK, Al + (size_t)row0 * GK,
        Bh + (size_t)col0 * GK, Bl + (size_t)col0 * GK };

    f32x4 acc[4][4];
#pragma unroll
    for (int mt = 0; mt < 4; ++mt)
#pragma unroll
        for (int nt = 0; nt < 4; ++nt) acc[mt][nt] = (f32x4)0.f;

    const int swz0 = ((0 + grp) ^ (fr & 7)) * 16;
    const int swz1 = ((4 + grp) ^ (fr & 7)) * 16;

    for (int k0 = 0; k0 < GK; k0 += 64) {
        __syncthreads();
#pragma unroll
        for (int t = 0; t < 4; ++t) {
            const _Float16* gsrc = srcs[t] + k0 + sc;
#pragma unroll
            for (int i = 0; i < 4; ++i) {
                int rb = wave * 32 + i * 8;
                gload16(gsrc + (size_t)(rb + dr) * GK, &lds[t][rb * 64]);
            }
        }
        __syncthreads();

        f16x8 fa[4][2][2];                  // [mt][ks][hi/lo]
#pragma unroll
        for (int mt = 0; mt < 4; ++mt) {
            int rbyte = (wr * 64 + mt * 16 + fr) * 128;
            fa[mt][0][0] = *(const f16x8*)((const char*)lds[0] + rbyte + swz0);
            fa[mt][1][0] = *(const f16x8*)((const char*)lds[0] + rbyte + swz1);
            fa[mt][0][1] = *(const f16x8*)((const char*)lds[1] + rbyte + swz0);
            fa[mt][1][1] = *(const f16x8*)((const char*)lds[1] + rbyte + swz1);
        }
#pragma unroll
        for (int nt = 0; nt < 4; ++nt) {
            int rbyte = (wc * 64 + nt * 16 + fr) * 128;
            f16x8 bh0 = *(const f16x8*)((const char*)lds[2] + rbyte + swz0);
            f16x8 bh1 = *(const f16x8*)((const char*)lds[2] + rbyte + swz1);
            f16x8 bl0 = *(const f16x8*)((const char*)lds[3] + rbyte + swz0);
            f16x8 bl1 = *(const f16x8*)((const char*)lds[3] + rbyte + swz1);
#pragma unroll
            for (int mt = 0; mt < 4; ++mt) {
                acc[mt][nt] = __builtin_amdgcn_mfma_f32_16x16x32_f16(fa[mt][0][0], bh0, acc[mt][nt], 0, 0, 0);
                acc[mt][nt] = __builtin_amdgcn_mfma_f32_16x16x32_f16(fa[mt][0][0], bl0, acc[mt][nt], 0, 0, 0);
                acc[mt][nt] = __builtin_amdgcn_mfma_f32_16x16x32_f16(fa[mt][0][1], bh0, acc[mt][nt], 0, 0, 0);
                acc[mt][nt] = __builtin_amdgcn_mfma_f32_16x16x32_f16(fa[mt][1][0], bh1, acc[mt][nt], 0, 0, 0);
                acc[mt][nt] = __builtin_amdgcn_mfma_f32_16x16x32_f16(fa[mt][1][0], bl1, acc[mt][nt], 0, 0, 0);
                acc[mt][nt] = __builtin_amdgcn_mfma_f32_16x16x32_f16(fa[mt][1][1], bh1, acc[mt][nt], 0, 0, 0);
            }
        }
    }

#pragma unroll
    for (int mt = 0; mt < 4; ++mt)
#pragma unroll
        for (int nt = 0; nt < 4; ++nt) {
            int col = col0 + wc * 64 + nt * 16 + fr;
            float bv = 0.f;
            if (EPI) bv = bias[col];
#pragma unroll
            for (int r = 0; r < 4; ++r) {
                int row = row0 + wr * 64 + mt * 16 + grp * 4 + r;
                float v = acc[mt][nt][r];
                if (EPI) v = fminf(fmaxf(v + bv, -10.f), 10.f);
                C[(size_t)row * N + col] = v;
            }
        }
}

// ---------------- scores = sum(q^2); also emit q f16 (hi only) --------------
__global__ __launch_bounds__(256) void score_kernel(
    const float* __restrict__ qkv, float* __restrict__ scores,
    _Float16* __restrict__ q_h)
{
    int w = blockIdx.x * 4 + (threadIdx.x >> 6);
    int lane = threadIdx.x & 63;
    int bh = w >> 11;
    int n = w & (N_ - 1);
    int b = bh / H_, h = bh % H_;
    float q = qkv[((size_t)b * N_ + n) * (3 * C_) + (size_t)h * HD_ + lane];
    q_h[((size_t)bh * N_ + n) * HD_ + lane] = (_Float16)q;
    float ss = q * q;
#pragma unroll
    for (int off = 32; off; off >>= 1) ss += __shfl_xor(ss, off);
    if (lane == 0) scores[(size_t)bh * N_ + n] = ss;
}

// ---------------- top-1024 of 2048 per (b,h): bitonic sort ------------------
__global__ __launch_bounds__(1024) void topk_kernel(
    const float* __restrict__ scores, int* __restrict__ keepidx)
{
    __shared__ unsigned long long keys[N_];
    const int bh = blockIdx.x;
    const int tid = threadIdx.x;
    const float* sc = scores + (size_t)bh * N_;
    for (int i = tid; i < N_; i += 1024) {
        unsigned fb = __float_as_uint(sc[i]);
        keys[i] = ((unsigned long long)fb << 32) | (unsigned)(N_ - 1 - i);
    }
    __syncthreads();
    for (int k = 2; k <= N_; k <<= 1) {
        for (int j = k >> 1; j > 0; j >>= 1) {
            for (int i = tid; i < N_; i += 1024) {
                int ixj = i ^ j;
                if (ixj > i) {
                    unsigned long long a = keys[i], b = keys[ixj];
                    bool desc = ((i & k) == 0);
                    if (desc ? (a < b) : (a > b)) { keys[i] = b; keys[ixj] = a; }
                }
            }
            __syncthreads();
        }
    }
    if (tid < KEEP_) {
        keepidx[(size_t)bh * KEEP_ + tid] = (N_ - 1) - (int)(keys[tid] & 0xffffffffu);
    }
}

// ---------------- gather: K f16 hi/lo row-major; V^T bf16 hi/lo -------------
__global__ __launch_bounds__(256) void gather_kernel(
    const float* __restrict__ qkv, const int* __restrict__ keepidx,
    _Float16* __restrict__ k_h, _Float16* __restrict__ k_l,
    unsigned short* __restrict__ vT_h, unsigned short* __restrict__ vT_l)
{
    __shared__ float vS[64][65];
    const int bh = blockIdx.x >> 4;
    const int chunk = blockIdx.x & 15;
    const int b = bh / H_, h = bh % H_;
    const int wave = threadIdx.x >> 6, lane = threadIdx.x & 63;
    const int j0 = chunk * 64;

#pragma unroll
    for (int jj = 0; jj < 16; ++jj) {
        int j = wave * 16 + jj;
        int n = keepidx[(size_t)bh * KEEP_ + j0 + j];
        size_t base = ((size_t)b * N_ + n) * (3 * C_) + (size_t)h * HD_ + lane;
        float kv = qkv[base + C_];
        float vv = qkv[base + 2 * C_];
        _Float16 kh = (_Float16)kv;
        size_t ko = ((size_t)bh * KEEP_ + j0 + j) * HD_ + lane;
        k_h[ko] = kh;
        k_l[ko] = (_Float16)(kv - (float)kh);
        vS[j][lane] = vv;
    }
    __syncthreads();
#pragma unroll
    for (int dd = 0; dd < 16; ++dd) {
        int d = wave * 16 + dd;
        float vv = vS[lane][d];
        unsigned short vh = f2bf(vv);
        size_t vo = ((size_t)bh * HD_ + d) * KEEP_ + j0 + lane;
        vT_h[vo] = vh;
        vT_l[vo] = f2bf(vv - bf2f(vh));
    }
}

// ---------------- MFMA flash attention (fixed-ref-50 softmax) ---------------
// block: (bh, 64 q-rows), 4 waves x 16 rows. K-tiles of 64 keys.
// QK: f16 2-product; PV: bf16 2-product; no per-tile reduces, no rescale.
// Epilogue writes f16 hi/lo split directly (feeds proj GEMM).
__global__ __launch_bounds__(256) void attn_kernel(
    const _Float16* __restrict__ q_h,
    const _Float16* __restrict__ k_h, const _Float16* __restrict__ k_l,
    const unsigned short* __restrict__ vT_h, const unsigned short* __restrict__ vT_l,
    _Float16* __restrict__ aoh, _Float16* __restrict__ aol)
{
    // XCD-chunked swizzle: nwg=1536 = 8*192 (bijective)
    int bid = ((int)blockIdx.x & 7) * 192 + ((int)blockIdx.x >> 3);
    const int bh = bid >> 5;       // 32 q-tiles of 64 rows
    const int qt = bid & 31;
    const int b = bh / H_, h = bh - b * H_;
    const int wave = threadIdx.x >> 6;
    const int lane = threadIdx.x & 63;
    const int row16 = lane & 15;
    const int grp = lane >> 4;

    __shared__ unsigned short pH[4][16][72];   // per-wave P tile (bf16)

    const int n0 = qt * 64 + wave * 16;

    // persistent Q A-frags (f16 hi only)
    f16x8 aQ[2];
#pragma unroll
    for (int ks = 0; ks < 2; ++ks)
        aQ[ks] = *reinterpret_cast<const f16x8*>(
            q_h + ((size_t)bh * N_ + n0 + row16) * HD_ + ks * 32 + grp * 8);

    f32x4 o[4];
    float ps[4];
#pragma unroll
    for (int nt = 0; nt < 4; ++nt) o[nt] = (f32x4)0.f;
#pragma unroll
    for (int r = 0; r < 4; ++r) ps[r] = 1e-30f;

    for (int t = 0; t < KEEP_ / 64; ++t) {
        // ---- S = Q K^T (f16, 2-product) ----
        f32x4 sv[4];
#pragma unroll
        for (int nt = 0; nt < 4; ++nt) sv[nt] = (f32x4)0.f;
#pragma unroll
        for (int nt = 0; nt < 4; ++nt) {
            size_t koff = ((size_t)bh * KEEP_ + t * 64 + nt * 16 + row16) * HD_ + grp * 8;
            f16x8 kh0 = *reinterpret_cast<const f16x8*>(k_h + koff);
            f16x8 kh1 = *reinterpret_cast<const f16x8*>(k_h + koff + 32);
            f16x8 kl0 = *reinterpret_cast<const f16x8*>(k_l + koff);
            f16x8 kl1 = *reinterpret_cast<const f16x8*>(k_l + koff + 32);
            sv[nt] = __builtin_amdgcn_mfma_f32_16x16x32_f16(aQ[0], kh0, sv[nt], 0, 0, 0);
            sv[nt] = __builtin_amdgcn_mfma_f32_16x16x32_f16(aQ[0], kl0, sv[nt], 0, 0, 0);
            sv[nt] = __builtin_amdgcn_mfma_f32_16x16x32_f16(aQ[1], kh1, sv[nt], 0, 0, 0);
            sv[nt] = __builtin_amdgcn_mfma_f32_16x16x32_f16(aQ[1], kl1, sv[nt], 0, 0, 0);
        }
        // ---- softmax vs fixed reference 50 (== softmax after clip) ----
#pragma unroll
        for (int nt = 0; nt < 4; ++nt)
#pragma unroll
            for (int r = 0; r < 4; ++r) {
                float x = fminf(fmaxf(sv[nt][r] * 0.125f, -50.f), 50.f);
                float p = __expf(x - 50.f);
                unsigned short ph = f2bf(p);
                ps[r] += bf2f(ph);              // sum exactly what PV consumes
                pH[wave][grp * 4 + r][nt * 16 + row16] = ph;
            }
        // ---- O += P V (bf16, 2-product); P via per-wave LDS round-trip ----
        short8v aP[2];
#pragma unroll
        for (int ks = 0; ks < 2; ++ks)
            aP[ks] = *reinterpret_cast<const short8v*>(&pH[wave][row16][ks * 32 + grp * 8]);
#pragma unroll
        for (int nt = 0; nt < 4; ++nt) {
            size_t voff = ((size_t)bh * HD_ + nt * 16 + row16) * KEEP_ + t * 64 + grp * 8;
            short8v vh0 = *reinterpret_cast<const short8v*>(vT_h + voff);
            short8v vh1 = *reinterpret_cast<const short8v*>(vT_h + voff + 32);
            short8v vl0 = *reinterpret_cast<const short8v*>(vT_l + voff);
            short8v vl1 = *reinterpret_cast<const short8v*>(vT_l + voff + 32);
            o[nt] = __builtin_amdgcn_mfma_f32_16x16x32_bf16(aP[0], vh0, o[nt], 0, 0, 0);
            o[nt] = __builtin_amdgcn_mfma_f32_16x16x32_bf16(aP[0], vl0, o[nt], 0, 0, 0);
            o[nt] = __builtin_amdgcn_mfma_f32_16x16x32_bf16(aP[1], vh1, o[nt], 0, 0, 0);
            o[nt] = __builtin_amdgcn_mfma_f32_16x16x32_bf16(aP[1], vl1, o[nt], 0, 0, 0);
        }
    }

    // ---- one deferred row-sum reduce (16-lane groups share rows) ----
#pragma unroll
    for (int off = 1; off < 16; off <<= 1)
#pragma unroll
        for (int r = 0; r < 4; ++r) ps[r] += __shfl_xor(ps[r], off);

    // ---- epilogue: normalize + write f16 hi/lo split of attn output ----
#pragma unroll
    for (int nt = 0; nt < 4; ++nt)
#pragma unroll
        for (int r = 0; r < 4; ++r) {
            int n = n0 + grp * 4 + r;
            int d = nt * 16 + row16;
            float v = o[nt][r] / ps[r];
            _Float16 hi = (_Float16)v;
            size_t oo = ((size_t)b * N_ + n) * C_ + (size_t)h * HD_ + d;
            aoh[oo] = hi;
            aol[oo] = (_Float16)(v - (float)hi);
        }
}

// ---------------------------------------------------------------------------
extern "C" void kernel_launch(void* const* d_in, const int* in_sizes, int n_in,
                              void* d_out, int out_size, void* d_ws, size_t ws_size,
                              hipStream_t stream)
{
    const float* x      = (const float*)d_in[0];
    const float* w_qkv  = (const float*)d_in[1];
    const float* w_proj = (const float*)d_in[2];
    const float* b_proj = (const float*)d_in[3];
    float* out = (float*)d_out;

    char* cur = (char*)d_ws;
    float* qkv = (float*)cur;              cur += (size_t)B_ * N_ * 3 * C_ * 4;       // 75.5 MB
    float* scores = (float*)cur;           cur += (size_t)BH_ * N_ * 4;
    int* keepidx = (int*)cur;              cur += (size_t)BH_ * KEEP_ * 4;
    // 25.2 MB region, 2 lifetimes: xh/xl (GEMM1) -> q_h (attn)
    char* shared25 = cur;                  cur += (size_t)BH_ * N_ * HD_ * 2 * 2;
    _Float16* k_h = (_Float16*)cur;        cur += (size_t)BH_ * KEEP_ * HD_ * 2;
    _Float16* k_l = (_Float16*)cur;        cur += (size_t)BH_ * KEEP_ * HD_ * 2;
    unsigned short* vT_h = (unsigned short*)cur; cur += (size_t)BH_ * HD_ * KEEP_ * 2;
    unsigned short* vT_l = (unsigned short*)cur; cur += (size_t)BH_ * HD_ * KEEP_ * 2;
    _Float16* wTh = (_Float16*)cur;        cur += (size_t)(3 * C_) * GK * 2;
    _Float16* wTl = (_Float16*)cur;        cur += (size_t)(3 * C_) * GK * 2;

    _Float16* xh = (_Float16*)shared25;
    _Float16* xl = xh + (size_t)B_ * N_ * C_;
    _Float16* q_h = (_Float16*)shared25;
    // attn output (f16 hi/lo) lives in the dead qkv region
    _Float16* aoh = (_Float16*)qkv;
    _Float16* aol = aoh + (size_t)B_ * N_ * C_;

    const int n4x = (B_ * N_ * C_) / 4;

    // 1) split x; transpose+split w_qkv; qkv = x @ w_qkv (MFMA split-f16)
    split4_kernel<<<n4x / 256, 256, 0, stream>>>(x, xh, xl, n4x);
    tsplit_kernel<<<dim3((3 * C_) / 32, GK / 32), 256, 0, stream>>>(w_qkv, wTh, wTl, 3 * C_);
    mfma_gemm<false><<<(B_ * N_ / 128) * (3 * C_ / 128), 256, 0, stream>>>(
        xh, xl, wTh, wTl, qkv, 3 * C_, nullptr, (3 * C_) / 128, (B_ * N_ / 128) * (3 * C_ / 128) / 8);
    // 2) scores + q f16 (overwrites xh/xl — x dead)
    score_kernel<<<(BH_ * N_) / 4, 256, 0, stream>>>(qkv, scores, q_h);
    // 3) top-k
    topk_kernel<<<BH_, 1024, 0, stream>>>(scores, keepidx);
    // 4) gather K f16 hi/lo + V^T bf16 hi/lo
    gather_kernel<<<BH_ * (KEEP_ / 64), 256, 0, stream>>>(qkv, keepidx, k_h, k_l, vT_h, vT_l);
    // 5) attention -> aoh/aol f16 split (into dead qkv region)
    attn_kernel<<<BH_ * (N_ / 64), 256, 0, stream>>>(q_h, k_h, k_l, vT_h, vT_l, aoh, aol);
    // 6) transpose+split w_proj; out = clip(ao @ w_proj + b, -10, 10)
    tsplit_kernel<<<dim3(C_ / 32, GK / 32), 256, 0, stream>>>(w_proj, wTh, wTl, C_);
    mfma_gemm<true><<<(B_ * N_ / 128) * (C_ / 128), 256, 0, stream>>>(
        aoh, aol, wTh, wTl, out, C_, b_proj, C_ / 128, (B_ * N_ / 128) * (C_ / 128) / 8);
}

// Round 6
// 330.485 us; speedup vs baseline: 2.0822x; 2.0822x over previous
//
#include <hip/hip_runtime.h>
#include <hip/hip_bf16.h>
#include <math.h>

// ---------------------------------------------------------------------------
// BiFormerAttention: B=4, N=2048, C=768, H=12, hd=64, keep=1024
// GEMMs: MFMA f16 3-product split (fp32-grade -> top-k set preserved).
// Attention: fixed-ref-50 softmax (exact softmax after clip +-50),
//   QK = Qhi(f16) x K(f16 hi/lo); PV = P(bf16) x V(bf16 hi/lo).
//   K/V tiles block-staged in LDS (global_load_lds, swizzled) — R5's
//   direct-global loads were the latency wall (MfmaUtil 4.4%).
// ---------------------------------------------------------------------------

#define B_  4
#define N_  2048
#define C_  768
#define H_  12
#define HD_ 64
#define KEEP_ 1024
#define BH_ (B_ * H_)
#define GK  768   // K dim of both big GEMMs

typedef __attribute__((ext_vector_type(8))) short short8v;     // 8 bf16
typedef __attribute__((ext_vector_type(4))) float f32x4;       // MFMA C/D
typedef __attribute__((ext_vector_type(8))) _Float16 f16x8;    // 8 fp16
typedef __attribute__((ext_vector_type(4))) _Float16 f16x4;

__device__ inline unsigned short f2bf(float f) {               // RNE f32->bf16
    unsigned u = __float_as_uint(f);
    unsigned r = (u + 0x7fffu + ((u >> 16) & 1u)) >> 16;
    return (unsigned short)r;
}
__device__ inline float bf2f(unsigned short h) {
    return __uint_as_float(((unsigned)h) << 16);
}

__device__ inline void gload16(const void* g, void* l) {
    __builtin_amdgcn_global_load_lds(
        (const __attribute__((address_space(1))) unsigned int*)(g),
        (__attribute__((address_space(3))) unsigned int*)(l), 16, 0, 0);
}

// ---------------- elementwise split: fp32 -> f16 hi + f16 lo ----------------
__global__ __launch_bounds__(256) void split4_kernel(
    const float* __restrict__ in, _Float16* __restrict__ hi,
    _Float16* __restrict__ lo, int n4)
{
    int i = blockIdx.x * 256 + threadIdx.x;
    if (i >= n4) return;
    float4 v = reinterpret_cast<const float4*>(in)[i];
    f16x4 h, l;
    h[0] = (_Float16)v.x; l[0] = (_Float16)(v.x - (float)h[0]);
    h[1] = (_Float16)v.y; l[1] = (_Float16)(v.y - (float)h[1]);
    h[2] = (_Float16)v.z; l[2] = (_Float16)(v.z - (float)h[2]);
    h[3] = (_Float16)v.w; l[3] = (_Float16)(v.w - (float)h[3]);
    reinterpret_cast<f16x4*>(hi)[i] = h;
    reinterpret_cast<f16x4*>(lo)[i] = l;
}

// ---------------- transpose + split: W[K][N] fp32 -> T[N][GK] f16 hi/lo -----
__global__ __launch_bounds__(256) void tsplit_kernel(
    const float* __restrict__ W, _Float16* __restrict__ Th,
    _Float16* __restrict__ Tl, int N)
{
    __shared__ float t[32][33];
    int n0 = blockIdx.x * 32, k0 = blockIdx.y * 32;
    int r = threadIdx.x >> 3, c4 = (threadIdx.x & 7) << 2;
    float4 v = *reinterpret_cast<const float4*>(&W[(size_t)(k0 + r) * N + n0 + c4]);
    t[r][c4 + 0] = v.x; t[r][c4 + 1] = v.y; t[r][c4 + 2] = v.z; t[r][c4 + 3] = v.w;
    __syncthreads();
#pragma unroll
    for (int j = 0; j < 4; ++j) {
        float val = t[c4 + j][r];                 // = W[k0+c4+j][n0+r]
        _Float16 h = (_Float16)val;
        size_t o = (size_t)(n0 + r) * GK + k0 + c4 + j;
        Th[o] = h;
        Tl[o] = (_Float16)(val - (float)h);
    }
}

// ---------------- MFMA split-f16 GEMM: C[M][N] = A[M][GK] * B^T[N][GK] ------
template <bool EPI>
__global__ __launch_bounds__(256, 2) void mfma_gemm(
    const _Float16* __restrict__ Ah, const _Float16* __restrict__ Al,
    const _Float16* __restrict__ Bh, const _Float16* __restrict__ Bl,
    float* __restrict__ C, int N, const float* __restrict__ bias,
    int gx, int cpx)
{
    __shared__ _Float16 lds[4][128 * 64];   // Ah,Al,Bh,Bl tiles (64 KiB)

    const int sb = ((int)blockIdx.x & 7) * cpx + ((int)blockIdx.x >> 3);
    const int bx = sb % gx, by = sb / gx;
    const int row0 = by * 128, col0 = bx * 128;

    const int tid = threadIdx.x;
    const int wave = tid >> 6, lane = tid & 63;
    const int fr = lane & 15, grp = lane >> 4;
    const int wr = wave >> 1, wc = wave & 1;

    const int dr = lane >> 3, ch = lane & 7;
    const int sc = (ch ^ dr) * 8;           // pre-swizzled source chunk

    const _Float16* srcs[4] = {
        Ah + (size_t)row0 * GK, Al + (size_t)row0 * GK,
        Bh + (size_t)col0 * GK, Bl + (size_t)col0 * GK };

    f32x4 acc[4][4];
#pragma unroll
    for (int mt = 0; mt < 4; ++mt)
#pragma unroll
        for (int nt = 0; nt < 4; ++nt) acc[mt][nt] = (f32x4)0.f;

    const int swz0 = ((0 + grp) ^ (fr & 7)) * 16;
    const int swz1 = ((4 + grp) ^ (fr & 7)) * 16;

    for (int k0 = 0; k0 < GK; k0 += 64) {
        __syncthreads();
#pragma unroll
        for (int t = 0; t < 4; ++t) {
            const _Float16* gsrc = srcs[t] + k0 + sc;
#pragma unroll
            for (int i = 0; i < 4; ++i) {
                int rb = wave * 32 + i * 8;
                gload16(gsrc + (size_t)(rb + dr) * GK, &lds[t][rb * 64]);
            }
        }
        __syncthreads();

        f16x8 fa[4][2][2];                  // [mt][ks][hi/lo]
#pragma unroll
        for (int mt = 0; mt < 4; ++mt) {
            int rbyte = (wr * 64 + mt * 16 + fr) * 128;
            fa[mt][0][0] = *(const f16x8*)((const char*)lds[0] + rbyte + swz0);
            fa[mt][1][0] = *(const f16x8*)((const char*)lds[0] + rbyte + swz1);
            fa[mt][0][1] = *(const f16x8*)((const char*)lds[1] + rbyte + swz0);
            fa[mt][1][1] = *(const f16x8*)((const char*)lds[1] + rbyte + swz1);
        }
#pragma unroll
        for (int nt = 0; nt < 4; ++nt) {
            int rbyte = (wc * 64 + nt * 16 + fr) * 128;
            f16x8 bh0 = *(const f16x8*)((const char*)lds[2] + rbyte + swz0);
            f16x8 bh1 = *(const f16x8*)((const char*)lds[2] + rbyte + swz1);
            f16x8 bl0 = *(const f16x8*)((const char*)lds[3] + rbyte + swz0);
            f16x8 bl1 = *(const f16x8*)((const char*)lds[3] + rbyte + swz1);
#pragma unroll
            for (int mt = 0; mt < 4; ++mt) {
                acc[mt][nt] = __builtin_amdgcn_mfma_f32_16x16x32_f16(fa[mt][0][0], bh0, acc[mt][nt], 0, 0, 0);
                acc[mt][nt] = __builtin_amdgcn_mfma_f32_16x16x32_f16(fa[mt][0][0], bl0, acc[mt][nt], 0, 0, 0);
                acc[mt][nt] = __builtin_amdgcn_mfma_f32_16x16x32_f16(fa[mt][0][1], bh0, acc[mt][nt], 0, 0, 0);
                acc[mt][nt] = __builtin_amdgcn_mfma_f32_16x16x32_f16(fa[mt][1][0], bh1, acc[mt][nt], 0, 0, 0);
                acc[mt][nt] = __builtin_amdgcn_mfma_f32_16x16x32_f16(fa[mt][1][0], bl1, acc[mt][nt], 0, 0, 0);
                acc[mt][nt] = __builtin_amdgcn_mfma_f32_16x16x32_f16(fa[mt][1][1], bh1, acc[mt][nt], 0, 0, 0);
            }
        }
    }

#pragma unroll
    for (int mt = 0; mt < 4; ++mt)
#pragma unroll
        for (int nt = 0; nt < 4; ++nt) {
            int col = col0 + wc * 64 + nt * 16 + fr;
            float bv = 0.f;
            if (EPI) bv = bias[col];
#pragma unroll
            for (int r = 0; r < 4; ++r) {
                int row = row0 + wr * 64 + mt * 16 + grp * 4 + r;
                float v = acc[mt][nt][r];
                if (EPI) v = fminf(fmaxf(v + bv, -10.f), 10.f);
                C[(size_t)row * N + col] = v;
            }
        }
}

// ---------------- scores = sum(q^2); also emit q f16 (hi only) --------------
__global__ __launch_bounds__(256) void score_kernel(
    const float* __restrict__ qkv, float* __restrict__ scores,
    _Float16* __restrict__ q_h)
{
    int w = blockIdx.x * 4 + (threadIdx.x >> 6);
    int lane = threadIdx.x & 63;
    int bh = w >> 11;
    int n = w & (N_ - 1);
    int b = bh / H_, h = bh % H_;
    float q = qkv[((size_t)b * N_ + n) * (3 * C_) + (size_t)h * HD_ + lane];
    q_h[((size_t)bh * N_ + n) * HD_ + lane] = (_Float16)q;
    float ss = q * q;
#pragma unroll
    for (int off = 32; off; off >>= 1) ss += __shfl_xor(ss, off);
    if (lane == 0) scores[(size_t)bh * N_ + n] = ss;
}

// ---------------- top-1024 of 2048 per (b,h): bitonic sort ------------------
__global__ __launch_bounds__(1024) void topk_kernel(
    const float* __restrict__ scores, int* __restrict__ keepidx)
{
    __shared__ unsigned long long keys[N_];
    const int bh = blockIdx.x;
    const int tid = threadIdx.x;
    const float* sc = scores + (size_t)bh * N_;
    for (int i = tid; i < N_; i += 1024) {
        unsigned fb = __float_as_uint(sc[i]);
        keys[i] = ((unsigned long long)fb << 32) | (unsigned)(N_ - 1 - i);
    }
    __syncthreads();
    for (int k = 2; k <= N_; k <<= 1) {
        for (int j = k >> 1; j > 0; j >>= 1) {
            for (int i = tid; i < N_; i += 1024) {
                int ixj = i ^ j;
                if (ixj > i) {
                    unsigned long long a = keys[i], b = keys[ixj];
                    bool desc = ((i & k) == 0);
                    if (desc ? (a < b) : (a > b)) { keys[i] = b; keys[ixj] = a; }
                }
            }
            __syncthreads();
        }
    }
    if (tid < KEEP_) {
        keepidx[(size_t)bh * KEEP_ + tid] = (N_ - 1) - (int)(keys[tid] & 0xffffffffu);
    }
}

// ---------------- gather: K f16 hi/lo row-major; V^T bf16 hi/lo -------------
__global__ __launch_bounds__(256) void gather_kernel(
    const float* __restrict__ qkv, const int* __restrict__ keepidx,
    _Float16* __restrict__ k_h, _Float16* __restrict__ k_l,
    unsigned short* __restrict__ vT_h, unsigned short* __restrict__ vT_l)
{
    __shared__ float vS[64][65];
    const int bh = blockIdx.x >> 4;
    const int chunk = blockIdx.x & 15;
    const int b = bh / H_, h = bh % H_;
    const int wave = threadIdx.x >> 6, lane = threadIdx.x & 63;
    const int j0 = chunk * 64;

#pragma unroll
    for (int jj = 0; jj < 16; ++jj) {
        int j = wave * 16 + jj;
        int n = keepidx[(size_t)bh * KEEP_ + j0 + j];
        size_t base = ((size_t)b * N_ + n) * (3 * C_) + (size_t)h * HD_ + lane;
        float kv = qkv[base + C_];
        float vv = qkv[base + 2 * C_];
        _Float16 kh = (_Float16)kv;
        size_t ko = ((size_t)bh * KEEP_ + j0 + j) * HD_ + lane;
        k_h[ko] = kh;
        k_l[ko] = (_Float16)(kv - (float)kh);
        vS[j][lane] = vv;
    }
    __syncthreads();
#pragma unroll
    for (int dd = 0; dd < 16; ++dd) {
        int d = wave * 16 + dd;
        float vv = vS[lane][d];
        unsigned short vh = f2bf(vv);
        size_t vo = ((size_t)bh * HD_ + d) * KEEP_ + j0 + lane;
        vT_h[vo] = vh;
        vT_l[vo] = f2bf(vv - bf2f(vh));
    }
}

// ---------------- MFMA flash attention (LDS-staged K/V) ---------------------
// block: (bh, 128 q-rows), 4 waves x 32 rows (mt=2). K-tiles of 64 keys.
// Per tile: wave w stages one of {Kh,Kl,Vh,Vl} (8 x gload16, source chunk
// pre-swizzled ch^(row&7)); all waves consume via swizzled ds_read_b128.
// Fixed-ref-50 softmax: no per-tile reduces, no rescale.
__global__ __launch_bounds__(256, 2) void attn_kernel(
    const _Float16* __restrict__ q_h,
    const _Float16* __restrict__ k_h, const _Float16* __restrict__ k_l,
    const unsigned short* __restrict__ vT_h, const unsigned short* __restrict__ vT_l,
    _Float16* __restrict__ aoh, _Float16* __restrict__ aol)
{
    // XCD-chunked swizzle: nwg=768 = 8*96 (bijective)
    int bid = ((int)blockIdx.x & 7) * 96 + ((int)blockIdx.x >> 3);
    const int bh = bid >> 4;       // 16 q-tiles of 128 rows
    const int qt = bid & 15;
    const int b = bh / H_, h = bh - b * H_;
    const int wave = threadIdx.x >> 6;
    const int lane = threadIdx.x & 63;
    const int row16 = lane & 15;
    const int grp = lane >> 4;

    __shared__ unsigned short sKV[4][64 * 64];   // Kh,Kl,Vh,Vl tiles (32 KiB)
    __shared__ unsigned short pH[4][32][72];     // per-wave P (bf16, 18 KiB)

    const int n0 = qt * 128 + wave * 32;

    // persistent Q A-frags (f16 hi only): [mt][ks]
    f16x8 aQ[2][2];
#pragma unroll
    for (int mt = 0; mt < 2; ++mt)
#pragma unroll
        for (int ks = 0; ks < 2; ++ks)
            aQ[mt][ks] = *reinterpret_cast<const f16x8*>(
                q_h + ((size_t)bh * N_ + n0 + mt * 16 + row16) * HD_ + ks * 32 + grp * 8);

    // staging role per wave
    const int dr = lane >> 3, ch = lane & 7;
    const int sc8 = (ch ^ dr) * 8;   // pre-swizzled source chunk (elems)
    const unsigned short* gbase;
    int rs, ts;                      // row stride, tile stride (elems)
    if (wave == 0)      { gbase = (const unsigned short*)k_h + (size_t)bh * KEEP_ * HD_; rs = 64;   ts = 64 * HD_; }
    else if (wave == 1) { gbase = (const unsigned short*)k_l + (size_t)bh * KEEP_ * HD_; rs = 64;   ts = 64 * HD_; }
    else if (wave == 2) { gbase = vT_h + (size_t)bh * HD_ * KEEP_;                        rs = KEEP_; ts = 64; }
    else                { gbase = vT_l + (size_t)bh * HD_ * KEEP_;                        rs = KEEP_; ts = 64; }
    unsigned short* ldst = sKV[wave];

    f32x4 o[2][4];
    float ps[2][4];
#pragma unroll
    for (int mt = 0; mt < 2; ++mt)
#pragma unroll
        for (int nt = 0; nt < 4; ++nt) o[mt][nt] = (f32x4)0.f;
#pragma unroll
    for (int mt = 0; mt < 2; ++mt)
#pragma unroll
        for (int r = 0; r < 4; ++r) ps[mt][r] = 1e-30f;

    const int swzA = ((0 + grp) ^ (row16 & 7)) * 8;   // ks=0 chunk (elems)
    const int swzB = ((4 + grp) ^ (row16 & 7)) * 8;   // ks=1

    for (int t = 0; t < KEEP_ / 64; ++t) {
        __syncthreads();             // previous tile fully consumed
#pragma unroll
        for (int i = 0; i < 8; ++i)
            gload16(gbase + (size_t)(i * 8 + dr) * rs + t * ts + sc8, ldst + i * 512);
        __syncthreads();             // vmcnt drained (compiler) + visibility

        // ---- S = Q K^T (f16, 2-product) ----
        f32x4 sv[2][4];
#pragma unroll
        for (int mt = 0; mt < 2; ++mt)
#pragma unroll
            for (int nt = 0; nt < 4; ++nt) sv[mt][nt] = (f32x4)0.f;
        const _Float16* sKh = (const _Float16*)sKV[0];
        const _Float16* sKl = (const _Float16*)sKV[1];
#pragma unroll
        for (int nt = 0; nt < 4; ++nt) {
            int rb = (nt * 16 + row16) * 64;
            f16x8 kh0 = *(const f16x8*)(sKh + rb + swzA);
            f16x8 kh1 = *(const f16x8*)(sKh + rb + swzB);
            f16x8 kl0 = *(const f16x8*)(sKl + rb + swzA);
            f16x8 kl1 = *(const f16x8*)(sKl + rb + swzB);
#pragma unroll
            for (int mt = 0; mt < 2; ++mt) {
                sv[mt][nt] = __builtin_amdgcn_mfma_f32_16x16x32_f16(aQ[mt][0], kh0, sv[mt][nt], 0, 0, 0);
                sv[mt][nt] = __builtin_amdgcn_mfma_f32_16x16x32_f16(aQ[mt][0], kl0, sv[mt][nt], 0, 0, 0);
                sv[mt][nt] = __builtin_amdgcn_mfma_f32_16x16x32_f16(aQ[mt][1], kh1, sv[mt][nt], 0, 0, 0);
                sv[mt][nt] = __builtin_amdgcn_mfma_f32_16x16x32_f16(aQ[mt][1], kl1, sv[mt][nt], 0, 0, 0);
            }
        }

        // ---- softmax vs fixed reference 50 (== softmax after clip) ----
#pragma unroll
        for (int mt = 0; mt < 2; ++mt)
#pragma unroll
            for (int nt = 0; nt < 4; ++nt)
#pragma unroll
                for (int r = 0; r < 4; ++r) {
                    float x = fminf(fmaxf(sv[mt][nt][r] * 0.125f, -50.f), 50.f);
                    float p = __expf(x - 50.f);
                    unsigned short ph = f2bf(p);
                    ps[mt][r] += bf2f(ph);       // sum exactly what PV consumes
                    pH[wave][mt * 16 + grp * 4 + r][nt * 16 + row16] = ph;
                }

        // ---- O += P V (bf16, 2-product) ----
        short8v aP[2][2];
#pragma unroll
        for (int mt = 0; mt < 2; ++mt)
#pragma unroll
            for (int ks = 0; ks < 2; ++ks)
                aP[mt][ks] = *reinterpret_cast<const short8v*>(
                    &pH[wave][mt * 16 + row16][ks * 32 + grp * 8]);
        const unsigned short* sVh = sKV[2];
        const unsigned short* sVl = sKV[3];
#pragma unroll
        for (int nt = 0; nt < 4; ++nt) {
            int rb = (nt * 16 + row16) * 64;
            short8v vh0 = *(const short8v*)(sVh + rb + swzA);
            short8v vh1 = *(const short8v*)(sVh + rb + swzB);
            short8v vl0 = *(const short8v*)(sVl + rb + swzA);
            short8v vl1 = *(const short8v*)(sVl + rb + swzB);
#pragma unroll
            for (int mt = 0; mt < 2; ++mt) {
                o[mt][nt] = __builtin_amdgcn_mfma_f32_16x16x32_bf16(aP[mt][0], vh0, o[mt][nt], 0, 0, 0);
                o[mt][nt] = __builtin_amdgcn_mfma_f32_16x16x32_bf16(aP[mt][0], vl0, o[mt][nt], 0, 0, 0);
                o[mt][nt] = __builtin_amdgcn_mfma_f32_16x16x32_bf16(aP[mt][1], vh1, o[mt][nt], 0, 0, 0);
                o[mt][nt] = __builtin_amdgcn_mfma_f32_16x16x32_bf16(aP[mt][1], vl1, o[mt][nt], 0, 0, 0);
            }
        }
    }

    // ---- one deferred row-sum reduce (across the 16 lanes of each grp) ----
#pragma unroll
    for (int off = 1; off < 16; off <<= 1)
#pragma unroll
        for (int mt = 0; mt < 2; ++mt)
#pragma unroll
            for (int r = 0; r < 4; ++r) ps[mt][r] += __shfl_xor(ps[mt][r], off);

    // ---- epilogue: normalize + write f16 hi/lo split of attn output ----
#pragma unroll
    for (int mt = 0; mt < 2; ++mt)
#pragma unroll
        for (int nt = 0; nt < 4; ++nt)
#pragma unroll
            for (int r = 0; r < 4; ++r) {
                int n = n0 + mt * 16 + grp * 4 + r;
                int d = nt * 16 + row16;
                float v = o[mt][nt][r] / ps[mt][r];
                _Float16 hi = (_Float16)v;
                size_t oo = ((size_t)b * N_ + n) * C_ + (size_t)h * HD_ + d;
                aoh[oo] = hi;
                aol[oo] = (_Float16)(v - (float)hi);
            }
}

// ---------------------------------------------------------------------------
extern "C" void kernel_launch(void* const* d_in, const int* in_sizes, int n_in,
                              void* d_out, int out_size, void* d_ws, size_t ws_size,
                              hipStream_t stream)
{
    const float* x      = (const float*)d_in[0];
    const float* w_qkv  = (const float*)d_in[1];
    const float* w_proj = (const float*)d_in[2];
    const float* b_proj = (const float*)d_in[3];
    float* out = (float*)d_out;

    char* cur = (char*)d_ws;
    float* qkv = (float*)cur;              cur += (size_t)B_ * N_ * 3 * C_ * 4;       // 75.5 MB
    float* scores = (float*)cur;           cur += (size_t)BH_ * N_ * 4;
    int* keepidx = (int*)cur;              cur += (size_t)BH_ * KEEP_ * 4;
    // 25.2 MB region, 2 lifetimes: xh/xl (GEMM1) -> q_h (attn)
    char* shared25 = cur;                  cur += (size_t)BH_ * N_ * HD_ * 2 * 2;
    _Float16* k_h = (_Float16*)cur;        cur += (size_t)BH_ * KEEP_ * HD_ * 2;
    _Float16* k_l = (_Float16*)cur;        cur += (size_t)BH_ * KEEP_ * HD_ * 2;
    unsigned short* vT_h = (unsigned short*)cur; cur += (size_t)BH_ * HD_ * KEEP_ * 2;
    unsigned short* vT_l = (unsigned short*)cur; cur += (size_t)BH_ * HD_ * KEEP_ * 2;
    _Float16* wTh = (_Float16*)cur;        cur += (size_t)(3 * C_) * GK * 2;
    _Float16* wTl = (_Float16*)cur;        cur += (size_t)(3 * C_) * GK * 2;

    _Float16* xh = (_Float16*)shared25;
    _Float16* xl = xh + (size_t)B_ * N_ * C_;
    _Float16* q_h = (_Float16*)shared25;
    // attn output (f16 hi/lo) lives in the dead qkv region
    _Float16* aoh = (_Float16*)qkv;
    _Float16* aol = aoh + (size_t)B_ * N_ * C_;

    const int n4x = (B_ * N_ * C_) / 4;

    // 1) split x; transpose+split w_qkv; qkv = x @ w_qkv (MFMA split-f16)
    split4_kernel<<<n4x / 256, 256, 0, stream>>>(x, xh, xl, n4x);
    tsplit_kernel<<<dim3((3 * C_) / 32, GK / 32), 256, 0, stream>>>(w_qkv, wTh, wTl, 3 * C_);
    mfma_gemm<false><<<(B_ * N_ / 128) * (3 * C_ / 128), 256, 0, stream>>>(
        xh, xl, wTh, wTl, qkv, 3 * C_, nullptr, (3 * C_) / 128, (B_ * N_ / 128) * (3 * C_ / 128) / 8);
    // 2) scores + q f16 (overwrites xh/xl — x dead)
    score_kernel<<<(BH_ * N_) / 4, 256, 0, stream>>>(qkv, scores, q_h);
    // 3) top-k
    topk_kernel<<<BH_, 1024, 0, stream>>>(scores, keepidx);
    // 4) gather K f16 hi/lo + V^T bf16 hi/lo
    gather_kernel<<<BH_ * (KEEP_ / 64), 256, 0, stream>>>(qkv, keepidx, k_h, k_l, vT_h, vT_l);
    // 5) attention -> aoh/aol f16 split (into dead qkv region)
    attn_kernel<<<BH_ * (N_ / 128), 256, 0, stream>>>(q_h, k_h, k_l, vT_h, vT_l, aoh, aol);
    // 6) transpose+split w_proj; out = clip(ao @ w_proj + b, -10, 10)
    tsplit_kernel<<<dim3(C_ / 32, GK / 32), 256, 0, stream>>>(w_proj, wTh, wTl, C_);
    mfma_gemm<true><<<(B_ * N_ / 128) * (C_ / 128), 256, 0, stream>>>(
        aoh, aol, wTh, wTl, out, C_, b_proj, C_ / 128, (B_ * N_ / 128) * (C_ / 128) / 8);
}

// Round 11
// 305.774 us; speedup vs baseline: 2.2505x; 1.0808x over previous
//
#include <hip/hip_runtime.h>
#include <hip/hip_bf16.h>
#include <math.h>

// ---------------------------------------------------------------------------
// BiFormerAttention: B=4, N=2048, C=768, H=12, hd=64, keep=1024
// QKV GEMM: q-blocks 3-product split-f16 (fp32-grade, feeds top-k) with
//   fused score+q_h epilogue (no q fp32 write); k/v blocks 2-product
//   (A-hi x B hi/lo), compacted [8192][1536] output.
// Proj GEMM: 2-product (A-hi x B hi/lo) + bias + clip.
// Attention: fixed-ref-50 softmax, LDS-staged K/V (R6 structure).
// ---------------------------------------------------------------------------

#define B_  4
#define N_  2048
#define C_  768
#define H_  12
#define HD_ 64
#define KEEP_ 1024
#define BH_ (B_ * H_)
#define GK  768    // K dim of both big GEMMs
#define KV2 1536   // compacted k/v row length

typedef __attribute__((ext_vector_type(8))) short short8v;     // 8 bf16
typedef __attribute__((ext_vector_type(4))) float f32x4;       // MFMA C/D
typedef __attribute__((ext_vector_type(8))) _Float16 f16x8;    // 8 fp16
typedef __attribute__((ext_vector_type(4))) _Float16 f16x4;

__device__ inline unsigned short f2bf(float f) {               // RNE f32->bf16
    unsigned u = __float_as_uint(f);
    unsigned r = (u + 0x7fffu + ((u >> 16) & 1u)) >> 16;
    return (unsigned short)r;
}
__device__ inline float bf2f(unsigned short h) {
    return __uint_as_float(((unsigned)h) << 16);
}

__device__ inline void gload16(const void* g, void* l) {
    __builtin_amdgcn_global_load_lds(
        (const __attribute__((address_space(1))) unsigned int*)(g),
        (__attribute__((address_space(3))) unsigned int*)(l), 16, 0, 0);
}

// ---------------- elementwise split: fp32 -> f16 hi + f16 lo ----------------
__global__ __launch_bounds__(256) void split4_kernel(
    const float* __restrict__ in, _Float16* __restrict__ hi,
    _Float16* __restrict__ lo, int n4)
{
    int i = blockIdx.x * 256 + threadIdx.x;
    if (i >= n4) return;
    float4 v = reinterpret_cast<const float4*>(in)[i];
    f16x4 h, l;
    h[0] = (_Float16)v.x; l[0] = (_Float16)(v.x - (float)h[0]);
    h[1] = (_Float16)v.y; l[1] = (_Float16)(v.y - (float)h[1]);
    h[2] = (_Float16)v.z; l[2] = (_Float16)(v.z - (float)h[2]);
    h[3] = (_Float16)v.w; l[3] = (_Float16)(v.w - (float)h[3]);
    reinterpret_cast<f16x4*>(hi)[i] = h;
    reinterpret_cast<f16x4*>(lo)[i] = l;
}

// ---------------- transpose + split: W[K][N] fp32 -> T[N][GK] f16 hi/lo -----
__global__ __launch_bounds__(256) void tsplit_kernel(
    const float* __restrict__ W, _Float16* __restrict__ Th,
    _Float16* __restrict__ Tl, int N)
{
    __shared__ float t[32][33];
    int n0 = blockIdx.x * 32, k0 = blockIdx.y * 32;
    int r = threadIdx.x >> 3, c4 = (threadIdx.x & 7) << 2;
    float4 v = *reinterpret_cast<const float4*>(&W[(size_t)(k0 + r) * N + n0 + c4]);
    t[r][c4 + 0] = v.x; t[r][c4 + 1] = v.y; t[r][c4 + 2] = v.z; t[r][c4 + 3] = v.w;
    __syncthreads();
#pragma unroll
    for (int j = 0; j < 4; ++j) {
        float val = t[c4 + j][r];                 // = W[k0+c4+j][n0+r]
        _Float16 h = (_Float16)val;
        size_t o = (size_t)(n0 + r) * GK + k0 + c4 + j;
        Th[o] = h;
        Tl[o] = (_Float16)(val - (float)h);
    }
}

// ---------------- MFMA split-f16 GEMM -----------------------------------
// MODE 0 (qkv): q-blocks (bx<6): 3-product, fused score/q_h epilogue, no C
//               write; kv-blocks: 2-product (A-hi), C compacted stride KV2.
// MODE 1 (proj): 2-product (A-hi), bias + clip epilogue, C stride C_.
template <int MODE>
__global__ __launch_bounds__(256, 2) void mfma_gemm(
    const _Float16* __restrict__ Ah, const _Float16* __restrict__ Al,
    const _Float16* __restrict__ Bh, const _Float16* __restrict__ Bl,
    float* __restrict__ C, const float* __restrict__ bias,
    float* __restrict__ scores, _Float16* __restrict__ q_h,
    int gx, int cpx)
{
    __shared__ _Float16 lds[4][128 * 64];   // Ah,Al,Bh,Bl tiles (64 KiB)

    const int sb = ((int)blockIdx.x & 7) * cpx + ((int)blockIdx.x >> 3);
    const int bx = sb % gx, by = sb / gx;
    const int row0 = by * 128, col0 = bx * 128;

    const bool qblk = (MODE == 0) && (bx < 6);

    const int tid = threadIdx.x;
    const int wave = tid >> 6, lane = tid & 63;
    const int fr = lane & 15, grp = lane >> 4;
    const int wr = wave >> 1, wc = wave & 1;

    const int dr = lane >> 3, ch = lane & 7;
    const int sc = (ch ^ dr) * 8;           // pre-swizzled source chunk

    const _Float16* srcs[4] = {
        Ah + (size_t)row0 * GK, Al + (size_t)row0 * GK,
        Bh + (size_t)col0 * GK, Bl + (size_t)col0 * GK };

    f32x4 acc[4][4];
#pragma unroll
    for (int mt = 0; mt < 4; ++mt)
#pragma unroll
        for (int nt = 0; nt < 4; ++nt) acc[mt][nt] = (f32x4)0.f;

    const int swz0 = ((0 + grp) ^ (fr & 7)) * 16;
    const int swz1 = ((4 + grp) ^ (fr & 7)) * 16;

    for (int k0 = 0; k0 < GK; k0 += 64) {
        __syncthreads();
#pragma unroll
        for (int t = 0; t < 4; ++t) {
            if (t == 1 && !qblk) continue;   // Al tile unused in 2-product
            const _Float16* gsrc = srcs[t] + k0 + sc;
#pragma unroll
            for (int i = 0; i < 4; ++i) {
                int rb = wave * 32 + i * 8;
                gload16(gsrc + (size_t)(rb + dr) * GK, &lds[t][rb * 64]);
            }
        }
        __syncthreads();

        if (qblk) {
            f16x8 fa[4][2][2];              // [mt][ks][hi/lo]
#pragma unroll
            for (int mt = 0; mt < 4; ++mt) {
                int rbyte = (wr * 64 + mt * 16 + fr) * 128;
                fa[mt][0][0] = *(const f16x8*)((const char*)lds[0] + rbyte + swz0);
                fa[mt][1][0] = *(const f16x8*)((const char*)lds[0] + rbyte + swz1);
                fa[mt][0][1] = *(const f16x8*)((const char*)lds[1] + rbyte + swz0);
                fa[mt][1][1] = *(const f16x8*)((const char*)lds[1] + rbyte + swz1);
            }
#pragma unroll
            for (int nt = 0; nt < 4; ++nt) {
                int rbyte = (wc * 64 + nt * 16 + fr) * 128;
                f16x8 bh0 = *(const f16x8*)((const char*)lds[2] + rbyte + swz0);
                f16x8 bh1 = *(const f16x8*)((const char*)lds[2] + rbyte + swz1);
                f16x8 bl0 = *(const f16x8*)((const char*)lds[3] + rbyte + swz0);
                f16x8 bl1 = *(const f16x8*)((const char*)lds[3] + rbyte + swz1);
#pragma unroll
                for (int mt = 0; mt < 4; ++mt) {
                    acc[mt][nt] = __builtin_amdgcn_mfma_f32_16x16x32_f16(fa[mt][0][0], bh0, acc[mt][nt], 0, 0, 0);
                    acc[mt][nt] = __builtin_amdgcn_mfma_f32_16x16x32_f16(fa[mt][0][0], bl0, acc[mt][nt], 0, 0, 0);
                    acc[mt][nt] = __builtin_amdgcn_mfma_f32_16x16x32_f16(fa[mt][0][1], bh0, acc[mt][nt], 0, 0, 0);
                    acc[mt][nt] = __builtin_amdgcn_mfma_f32_16x16x32_f16(fa[mt][1][0], bh1, acc[mt][nt], 0, 0, 0);
                    acc[mt][nt] = __builtin_amdgcn_mfma_f32_16x16x32_f16(fa[mt][1][0], bl1, acc[mt][nt], 0, 0, 0);
                    acc[mt][nt] = __builtin_amdgcn_mfma_f32_16x16x32_f16(fa[mt][1][1], bh1, acc[mt][nt], 0, 0, 0);
                }
            }
        } else {
            f16x8 fa[4][2];                 // [mt][ks] hi only
#pragma unroll
            for (int mt = 0; mt < 4; ++mt) {
                int rbyte = (wr * 64 + mt * 16 + fr) * 128;
                fa[mt][0] = *(const f16x8*)((const char*)lds[0] + rbyte + swz0);
                fa[mt][1] = *(const f16x8*)((const char*)lds[0] + rbyte + swz1);
            }
#pragma unroll
            for (int nt = 0; nt < 4; ++nt) {
                int rbyte = (wc * 64 + nt * 16 + fr) * 128;
                f16x8 bh0 = *(const f16x8*)((const char*)lds[2] + rbyte + swz0);
                f16x8 bh1 = *(const f16x8*)((const char*)lds[2] + rbyte + swz1);
                f16x8 bl0 = *(const f16x8*)((const char*)lds[3] + rbyte + swz0);
                f16x8 bl1 = *(const f16x8*)((const char*)lds[3] + rbyte + swz1);
#pragma unroll
                for (int mt = 0; mt < 4; ++mt) {
                    acc[mt][nt] = __builtin_amdgcn_mfma_f32_16x16x32_f16(fa[mt][0], bh0, acc[mt][nt], 0, 0, 0);
                    acc[mt][nt] = __builtin_amdgcn_mfma_f32_16x16x32_f16(fa[mt][0], bl0, acc[mt][nt], 0, 0, 0);
                    acc[mt][nt] = __builtin_amdgcn_mfma_f32_16x16x32_f16(fa[mt][1], bh1, acc[mt][nt], 0, 0, 0);
                    acc[mt][nt] = __builtin_amdgcn_mfma_f32_16x16x32_f16(fa[mt][1], bl1, acc[mt][nt], 0, 0, 0);
                }
            }
        }
    }

    if (MODE == 1) {
        // proj epilogue: bias + clip, C stride C_
#pragma unroll
        for (int mt = 0; mt < 4; ++mt)
#pragma unroll
            for (int nt = 0; nt < 4; ++nt) {
                int col = col0 + wc * 64 + nt * 16 + fr;
                float bv = bias[col];
#pragma unroll
                for (int r = 0; r < 4; ++r) {
                    int row = row0 + wr * 64 + mt * 16 + grp * 4 + r;
                    float v = fminf(fmaxf(acc[mt][nt][r] + bv, -10.f), 10.f);
                    C[(size_t)row * C_ + col] = v;
                }
            }
    } else if (!qblk) {
        // kv epilogue: compacted write, stride KV2, col-768
#pragma unroll
        for (int mt = 0; mt < 4; ++mt)
#pragma unroll
            for (int nt = 0; nt < 4; ++nt) {
                int col = col0 + wc * 64 + nt * 16 + fr - 768;
#pragma unroll
                for (int r = 0; r < 4; ++r) {
                    int row = row0 + wr * 64 + mt * 16 + grp * 4 + r;
                    C[(size_t)row * KV2 + col] = acc[mt][nt][r];
                }
            }
    } else {
        // q epilogue: fused score (sum q^2 over the wave's head) + q_h f16.
        // wave (wr,wc): rows row0+wr*64..+63, head = col0/64 + wc.
        const int hglob = (col0 >> 6) + wc;
#pragma unroll
        for (int mt = 0; mt < 4; ++mt)
#pragma unroll
            for (int r = 0; r < 4; ++r) {
                float ss = 0.f;
#pragma unroll
                for (int nt = 0; nt < 4; ++nt) ss += acc[mt][nt][r] * acc[mt][nt][r];
#pragma unroll
                for (int off = 1; off < 16; off <<= 1) ss += __shfl_xor(ss, off);
                int row = row0 + wr * 64 + mt * 16 + grp * 4 + r;
                int bb = row >> 11, n = row & (N_ - 1);
                size_t bhn = ((size_t)bb * H_ + hglob) * N_ + n;
                if (fr == 0) scores[bhn] = ss;
#pragma unroll
                for (int nt = 0; nt < 4; ++nt)
                    q_h[bhn * HD_ + nt * 16 + fr] = (_Float16)acc[mt][nt][r];
            }
    }
}

// ---------------- top-1024 of 2048 per (b,h): bitonic sort ------------------
__global__ __launch_bounds__(1024) void topk_kernel(
    const float* __restrict__ scores, int* __restrict__ keepidx)
{
    __shared__ unsigned long long keys[N_];
    const int bh = blockIdx.x;
    const int tid = threadIdx.x;
    const float* sc = scores + (size_t)bh * N_;
    for (int i = tid; i < N_; i += 1024) {
        unsigned fb = __float_as_uint(sc[i]);
        keys[i] = ((unsigned long long)fb << 32) | (unsigned)(N_ - 1 - i);
    }
    __syncthreads();
    for (int k = 2; k <= N_; k <<= 1) {
        for (int j = k >> 1; j > 0; j >>= 1) {
            for (int i = tid; i < N_; i += 1024) {
                int ixj = i ^ j;
                if (ixj > i) {
                    unsigned long long a = keys[i], b = keys[ixj];
                    bool desc = ((i & k) == 0);
                    if (desc ? (a < b) : (a > b)) { keys[i] = b; keys[ixj] = a; }
                }
            }
            __syncthreads();
        }
    }
    if (tid < KEEP_) {
        keepidx[(size_t)bh * KEEP_ + tid] = (N_ - 1) - (int)(keys[tid] & 0xffffffffu);
    }
}

// ---------------- gather: K f16 hi/lo row-major; V^T bf16 hi/lo -------------
__global__ __launch_bounds__(256) void gather_kernel(
    const float* __restrict__ kv, const int* __restrict__ keepidx,
    _Float16* __restrict__ k_h, _Float16* __restrict__ k_l,
    unsigned short* __restrict__ vT_h, unsigned short* __restrict__ vT_l)
{
    __shared__ float vS[64][65];
    const int bh = blockIdx.x >> 4;
    const int chunk = blockIdx.x & 15;
    const int b = bh / H_, h = bh % H_;
    const int wave = threadIdx.x >> 6, lane = threadIdx.x & 63;
    const int j0 = chunk * 64;

#pragma unroll
    for (int jj = 0; jj < 16; ++jj) {
        int j = wave * 16 + jj;
        int n = keepidx[(size_t)bh * KEEP_ + j0 + j];
        size_t base = ((size_t)b * N_ + n) * KV2 + (size_t)h * HD_ + lane;
        float kval = kv[base];
        float vv = kv[base + C_];
        _Float16 kh = (_Float16)kval;
        size_t ko = ((size_t)bh * KEEP_ + j0 + j) * HD_ + lane;
        k_h[ko] = kh;
        k_l[ko] = (_Float16)(kval - (float)kh);
        vS[j][lane] = vv;
    }
    __syncthreads();
#pragma unroll
    for (int dd = 0; dd < 16; ++dd) {
        int d = wave * 16 + dd;
        float vv = vS[lane][d];
        unsigned short vh = f2bf(vv);
        size_t vo = ((size_t)bh * HD_ + d) * KEEP_ + j0 + lane;
        vT_h[vo] = vh;
        vT_l[vo] = f2bf(vv - bf2f(vh));
    }
}

// ---------------- MFMA flash attention (LDS-staged K/V) ---------------------
__global__ __launch_bounds__(256, 2) void attn_kernel(
    const _Float16* __restrict__ q_h,
    const _Float16* __restrict__ k_h, const _Float16* __restrict__ k_l,
    const unsigned short* __restrict__ vT_h, const unsigned short* __restrict__ vT_l,
    _Float16* __restrict__ aoh)
{
    // XCD-chunked swizzle: nwg=768 = 8*96 (bijective)
    int bid = ((int)blockIdx.x & 7) * 96 + ((int)blockIdx.x >> 3);
    const int bh = bid >> 4;       // 16 q-tiles of 128 rows
    const int qt = bid & 15;
    const int b = bh / H_, h = bh - b * H_;
    const int wave = threadIdx.x >> 6;
    const int lane = threadIdx.x & 63;
    const int row16 = lane & 15;
    const int grp = lane >> 4;

    __shared__ unsigned short sKV[4][64 * 64];   // Kh,Kl,Vh,Vl tiles (32 KiB)
    __shared__ unsigned short pH[4][32][72];     // per-wave P (bf16, 18 KiB)

    const int n0 = qt * 128 + wave * 32;

    f16x8 aQ[2][2];
#pragma unroll
    for (int mt = 0; mt < 2; ++mt)
#pragma unroll
        for (int ks = 0; ks < 2; ++ks)
            aQ[mt][ks] = *reinterpret_cast<const f16x8*>(
                q_h + ((size_t)bh * N_ + n0 + mt * 16 + row16) * HD_ + ks * 32 + grp * 8);

    const int dr = lane >> 3, ch = lane & 7;
    const int sc8 = (ch ^ dr) * 8;
    const unsigned short* gbase;
    int rs, ts;
    if (wave == 0)      { gbase = (const unsigned short*)k_h + (size_t)bh * KEEP_ * HD_; rs = 64;   ts = 64 * HD_; }
    else if (wave == 1) { gbase = (const unsigned short*)k_l + (size_t)bh * KEEP_ * HD_; rs = 64;   ts = 64 * HD_; }
    else if (wave == 2) { gbase = vT_h + (size_t)bh * HD_ * KEEP_;                        rs = KEEP_; ts = 64; }
    else                { gbase = vT_l + (size_t)bh * HD_ * KEEP_;                        rs = KEEP_; ts = 64; }
    unsigned short* ldst = sKV[wave];

    f32x4 o[2][4];
    float ps[2][4];
#pragma unroll
    for (int mt = 0; mt < 2; ++mt)
#pragma unroll
        for (int nt = 0; nt < 4; ++nt) o[mt][nt] = (f32x4)0.f;
#pragma unroll
    for (int mt = 0; mt < 2; ++mt)
#pragma unroll
        for (int r = 0; r < 4; ++r) ps[mt][r] = 1e-30f;

    const int swzA = ((0 + grp) ^ (row16 & 7)) * 8;
    const int swzB = ((4 + grp) ^ (row16 & 7)) * 8;

    for (int t = 0; t < KEEP_ / 64; ++t) {
        __syncthreads();
#pragma unroll
        for (int i = 0; i < 8; ++i)
            gload16(gbase + (size_t)(i * 8 + dr) * rs + t * ts + sc8, ldst + i * 512);
        __syncthreads();

        f32x4 sv[2][4];
#pragma unroll
        for (int mt = 0; mt < 2; ++mt)
#pragma unroll
            for (int nt = 0; nt < 4; ++nt) sv[mt][nt] = (f32x4)0.f;
        const _Float16* sKh = (const _Float16*)sKV[0];
        const _Float16* sKl = (const _Float16*)sKV[1];
#pragma unroll
        for (int nt = 0; nt < 4; ++nt) {
            int rb = (nt * 16 + row16) * 64;
            f16x8 kh0 = *(const f16x8*)(sKh + rb + swzA);
            f16x8 kh1 = *(const f16x8*)(sKh + rb + swzB);
            f16x8 kl0 = *(const f16x8*)(sKl + rb + swzA);
            f16x8 kl1 = *(const f16x8*)(sKl + rb + swzB);
#pragma unroll
            for (int mt = 0; mt < 2; ++mt) {
                sv[mt][nt] = __builtin_amdgcn_mfma_f32_16x16x32_f16(aQ[mt][0], kh0, sv[mt][nt], 0, 0, 0);
                sv[mt][nt] = __builtin_amdgcn_mfma_f32_16x16x32_f16(aQ[mt][0], kl0, sv[mt][nt], 0, 0, 0);
                sv[mt][nt] = __builtin_amdgcn_mfma_f32_16x16x32_f16(aQ[mt][1], kh1, sv[mt][nt], 0, 0, 0);
                sv[mt][nt] = __builtin_amdgcn_mfma_f32_16x16x32_f16(aQ[mt][1], kl1, sv[mt][nt], 0, 0, 0);
            }
        }

#pragma unroll
        for (int mt = 0; mt < 2; ++mt)
#pragma unroll
            for (int nt = 0; nt < 4; ++nt)
#pragma unroll
                for (int r = 0; r < 4; ++r) {
                    float x = fminf(fmaxf(sv[mt][nt][r] * 0.125f, -50.f), 50.f);
                    float p = __expf(x - 50.f);
                    unsigned short ph = f2bf(p);
                    ps[mt][r] += bf2f(ph);
                    pH[wave][mt * 16 + grp * 4 + r][nt * 16 + row16] = ph;
                }

        short8v aP[2][2];
#pragma unroll
        for (int mt = 0; mt < 2; ++mt)
#pragma unroll
            for (int ks = 0; ks < 2; ++ks)
                aP[mt][ks] = *reinterpret_cast<const short8v*>(
                    &pH[wave][mt * 16 + row16][ks * 32 + grp * 8]);
        const unsigned short* sVh = sKV[2];
        const unsigned short* sVl = sKV[3];
#pragma unroll
        for (int nt = 0; nt < 4; ++nt) {
            int rb = (nt * 16 + row16) * 64;
            short8v vh0 = *(const short8v*)(sVh + rb + swzA);
            short8v vh1 = *(const short8v*)(sVh + rb + swzB);
            short8v vl0 = *(const short8v*)(sVl + rb + swzA);
            short8v vl1 = *(const short8v*)(sVl + rb + swzB);
#pragma unroll
            for (int mt = 0; mt < 2; ++mt) {
                o[mt][nt] = __builtin_amdgcn_mfma_f32_16x16x32_bf16(aP[mt][0], vh0, o[mt][nt], 0, 0, 0);
                o[mt][nt] = __builtin_amdgcn_mfma_f32_16x16x32_bf16(aP[mt][0], vl0, o[mt][nt], 0, 0, 0);
                o[mt][nt] = __builtin_amdgcn_mfma_f32_16x16x32_bf16(aP[mt][1], vh1, o[mt][nt], 0, 0, 0);
                o[mt][nt] = __builtin_amdgcn_mfma_f32_16x16x32_bf16(aP[mt][1], vl1, o[mt][nt], 0, 0, 0);
            }
        }
    }

#pragma unroll
    for (int off = 1; off < 16; off <<= 1)
#pragma unroll
        for (int mt = 0; mt < 2; ++mt)
#pragma unroll
            for (int r = 0; r < 4; ++r) ps[mt][r] += __shfl_xor(ps[mt][r], off);

#pragma unroll
    for (int mt = 0; mt < 2; ++mt)
#pragma unroll
        for (int nt = 0; nt < 4; ++nt)
#pragma unroll
            for (int r = 0; r < 4; ++r) {
                int n = n0 + mt * 16 + grp * 4 + r;
                int d = nt * 16 + row16;
                float v = o[mt][nt][r] / ps[mt][r];
                aoh[((size_t)b * N_ + n) * C_ + (size_t)h * HD_ + d] = (_Float16)v;
            }
}

// ---------------------------------------------------------------------------
extern "C" void kernel_launch(void* const* d_in, const int* in_sizes, int n_in,
                              void* d_out, int out_size, void* d_ws, size_t ws_size,
                              hipStream_t stream)
{
    const float* x      = (const float*)d_in[0];
    const float* w_qkv  = (const float*)d_in[1];
    const float* w_proj = (const float*)d_in[2];
    const float* b_proj = (const float*)d_in[3];
    float* out = (float*)d_out;

    char* cur = (char*)d_ws;
    float* kv = (float*)cur;               cur += (size_t)B_ * N_ * KV2 * 4;          // 50.3 MB
    float* scores = (float*)cur;           cur += (size_t)BH_ * N_ * 4;
    int* keepidx = (int*)cur;              cur += (size_t)BH_ * KEEP_ * 4;
    _Float16* xh = (_Float16*)cur;         cur += (size_t)B_ * N_ * C_ * 2;           // 12.6 (-> aoh)
    _Float16* xl = (_Float16*)cur;         cur += (size_t)B_ * N_ * C_ * 2;           // 12.6
    _Float16* q_h = (_Float16*)cur;        cur += (size_t)BH_ * N_ * HD_ * 2;         // 12.6
    _Float16* k_h = (_Float16*)cur;        cur += (size_t)BH_ * KEEP_ * HD_ * 2;
    _Float16* k_l = (_Float16*)cur;        cur += (size_t)BH_ * KEEP_ * HD_ * 2;
    unsigned short* vT_h = (unsigned short*)cur; cur += (size_t)BH_ * HD_ * KEEP_ * 2;
    unsigned short* vT_l = (unsigned short*)cur; cur += (size_t)BH_ * HD_ * KEEP_ * 2;
    _Float16* wTh = (_Float16*)cur;        cur += (size_t)(3 * C_) * GK * 2;
    _Float16* wTl = (_Float16*)cur;        cur += (size_t)(3 * C_) * GK * 2;

    _Float16* aoh = xh;   // xh dead after GEMM1; attn output reuses it

    const int n4x = (B_ * N_ * C_) / 4;

    // 1) split x; transpose+split w_qkv; fused qkv GEMM (q->scores/q_h, kv->kv)
    split4_kernel<<<n4x / 256, 256, 0, stream>>>(x, xh, xl, n4x);
    tsplit_kernel<<<dim3((3 * C_) / 32, GK / 32), 256, 0, stream>>>(w_qkv, wTh, wTl, 3 * C_);
    mfma_gemm<0><<<(B_ * N_ / 128) * (3 * C_ / 128), 256, 0, stream>>>(
        xh, xl, wTh, wTl, kv, nullptr, scores, q_h,
        (3 * C_) / 128, (B_ * N_ / 128) * (3 * C_ / 128) / 8);
    // 2) top-k
    topk_kernel<<<BH_, 1024, 0, stream>>>(scores, keepidx);
    // 3) gather K f16 hi/lo + V^T bf16 hi/lo
    gather_kernel<<<BH_ * (KEEP_ / 64), 256, 0, stream>>>(kv, keepidx, k_h, k_l, vT_h, vT_l);
    // 4) attention -> aoh f16 (aliases xh)
    attn_kernel<<<BH_ * (N_ / 128), 256, 0, stream>>>(q_h, k_h, k_l, vT_h, vT_l, aoh);
    // 5) transpose+split w_proj; out = clip(ao @ w_proj + b, -10, 10)
    tsplit_kernel<<<dim3(C_ / 32, GK / 32), 256, 0, stream>>>(w_proj, wTh, wTl, C_);
    mfma_gemm<1><<<(B_ * N_ / 128) * (C_ / 128), 256, 0, stream>>>(
        aoh, aoh, wTh, wTl, out, b_proj, nullptr, nullptr,
        C_ / 128, (B_ * N_ / 128) * (C_ / 128) / 8);
}